// Round 1
// baseline (568.026 us; speedup 1.0000x reference)
//
#include <hip/hip_runtime.h>
#include <hip/hip_bf16.h>

#define N_TOK 4096
#define D_IN  512
#define D_HID 256
#define N_OUT 40

typedef _Float16 half8 __attribute__((ext_vector_type(8)));
typedef _Float16 half4 __attribute__((ext_vector_type(4)));
typedef float    f32x4 __attribute__((ext_vector_type(4)));

// ---------------------------------------------------------------------------
// prep: h -> fp16; Wq/Wk/Wv -> transposed fp16 [head][256][512];
// Wo -> transposed fp16 [512][512]; Wp -> transposed+padded fp16 [48][512]
// ---------------------------------------------------------------------------
__global__ void prep_kernel(const float* __restrict__ h, const float* __restrict__ Wq,
                            const float* __restrict__ Wk, const float* __restrict__ Wv,
                            const float* __restrict__ Wo, const float* __restrict__ Wp,
                            _Float16* __restrict__ h16, _Float16* __restrict__ Wqt,
                            _Float16* __restrict__ Wkt, _Float16* __restrict__ Wvt,
                            _Float16* __restrict__ Wot, _Float16* __restrict__ Wpt)
{
  int b = blockIdx.x, tid = threadIdx.x;
  if (b < 1024) {                              // h -> h16 (4096x512)
    int base = b * 2048 + tid * 8;
    float4 x0 = *(const float4*)(h + base);
    float4 x1 = *(const float4*)(h + base + 4);
    half8 o;
    o[0]=(_Float16)x0.x; o[1]=(_Float16)x0.y; o[2]=(_Float16)x0.z; o[3]=(_Float16)x0.w;
    o[4]=(_Float16)x1.x; o[5]=(_Float16)x1.y; o[6]=(_Float16)x1.z; o[7]=(_Float16)x1.w;
    *(half8*)(h16 + base) = o;
  } else if (b < 1792) {                       // Wq/Wk/Wv transpose
    int sub = b - 1024;
    int pair = sub >> 7;                       // 0..5
    int blk  = sub & 127;
    int mat = pair >> 1, head = pair & 1;
    const float* W = (mat==0 ? Wq : (mat==1 ? Wk : Wv)) + head * (D_IN * D_HID);
    _Float16* Wt   = (mat==0 ? Wqt : (mat==1 ? Wkt : Wvt)) + head * (D_IN * D_HID);
    int idx = blk * 1024 + tid * 4;
    int d = idx >> 9;
    int i = idx & 511;
    half4 o;
#pragma unroll
    for (int u = 0; u < 4; u++) o[u] = (_Float16)W[(i + u) * D_HID + d];
    *(half4*)(Wt + d * D_IN + i) = o;
  } else if (b < 2048) {                       // Wo transpose (512x512)
    int blk = b - 1792;
    int idx = blk * 1024 + tid * 4;
    int d = idx >> 9, i = idx & 511;
    half4 o;
#pragma unroll
    for (int u = 0; u < 4; u++) o[u] = (_Float16)Wo[(i + u) * D_IN + d];
    *(half4*)(Wot + d * D_IN + i) = o;
  } else {                                     // Wp transpose+pad to [48][512]
    int blk = b - 2048;                        // 0..23
    int idx = blk * 1024 + tid * 4;
    int j = idx >> 9, i = idx & 511;
    half4 o;
#pragma unroll
    for (int u = 0; u < 4; u++)
      o[u] = (j < N_OUT) ? (_Float16)Wp[(i + u) * N_OUT + j] : (_Float16)0.f;
    *(half4*)(Wpt + j * D_IN + i) = o;
  }
}

// ---------------------------------------------------------------------------
// proj: Q/K/V = h16 @ W (+bias), fp16 out, row-major [head][4096][256]
// grid 768 = 6 (mat,head) x 128 row-tiles of 32; 4 waves: 2 strips x 2 col halves
// ---------------------------------------------------------------------------
__global__ __launch_bounds__(256, 2) void proj_kernel(
    const _Float16* __restrict__ h16,
    const _Float16* __restrict__ Wqt, const _Float16* __restrict__ Wkt,
    const _Float16* __restrict__ Wvt,
    const float* __restrict__ bq, const float* __restrict__ bk,
    const float* __restrict__ bv,
    _Float16* __restrict__ Q16, _Float16* __restrict__ K16,
    _Float16* __restrict__ V16)
{
  int b = blockIdx.x;
  int mh = b >> 7, tile = b & 127;
  int mat = mh >> 1, head = mh & 1;
  const _Float16* Wt = (mat==0 ? Wqt : (mat==1 ? Wkt : Wvt)) + head * (D_IN * D_HID);
  const float* bias  = (mat==0 ? bq  : (mat==1 ? bk  : bv )) + head * D_HID;
  _Float16* Out      = (mat==0 ? Q16 : (mat==1 ? K16 : V16)) + head * (N_TOK * D_HID);
  int tid = threadIdx.x, w = tid >> 6, lane = tid & 63, quad = lane >> 4, cL = lane & 15;
  int row = tile * 32 + (w >> 1) * 16;
  int ch = w & 1;
  const f32x4 z4 = {0.f, 0.f, 0.f, 0.f};
  half8 af[16];
#pragma unroll
  for (int t = 0; t < 16; t++)
    af[t] = *(const half8*)(h16 + (row + cL) * D_IN + t * 32 + quad * 8);
  f32x4 acc[8];
#pragma unroll
  for (int i = 0; i < 8; i++) acc[i] = z4;
#pragma unroll
  for (int t = 0; t < 16; t++) {
#pragma unroll
    for (int nt = 0; nt < 8; nt++) {
      half8 bf = *(const half8*)(Wt + (ch * 128 + nt * 16 + cL) * D_IN + t * 32 + quad * 8);
      acc[nt] = __builtin_amdgcn_mfma_f32_16x16x32_f16(af[t], bf, acc[nt], 0, 0, 0);
    }
  }
#pragma unroll
  for (int nt = 0; nt < 8; nt++) {
    int col = ch * 128 + nt * 16 + cL;
    float bb = bias[col];
#pragma unroll
    for (int reg = 0; reg < 4; reg++)
      Out[(row + quad * 4 + reg) * D_HID + col] = (_Float16)(acc[nt][reg] + bb);
  }
}

// ---------------------------------------------------------------------------
// transv: V [head][4096][256] -> VT [head][256][4096] via 64x64 LDS tiles
// ---------------------------------------------------------------------------
__global__ void transv_kernel(const _Float16* __restrict__ V16, _Float16* __restrict__ VT16)
{
  __shared__ __align__(16) _Float16 tile[64 * 72];
  int b = blockIdx.x;
  int head = b >> 8, lb = b & 255;
  int n0 = (lb >> 2) * 64, d0 = (lb & 3) * 64;
  const _Float16* Vh = V16 + head * (N_TOK * D_HID);
  _Float16* VTh = VT16 + head * (N_TOK * D_HID);
  int tid = threadIdx.x;
  int rr = tid >> 2, cg = tid & 3;
  half8 x0 = *(const half8*)(Vh + (n0 + rr) * D_HID + d0 + cg * 16);
  half8 x1 = *(const half8*)(Vh + (n0 + rr) * D_HID + d0 + cg * 16 + 8);
  *(half8*)(tile + rr * 72 + cg * 16) = x0;
  *(half8*)(tile + rr * 72 + cg * 16 + 8) = x1;
  __syncthreads();
  half8 o0, o1;
#pragma unroll
  for (int j = 0; j < 8; j++) {
    o0[j] = tile[(cg * 16 + j) * 72 + rr];
    o1[j] = tile[(cg * 16 + 8 + j) * 72 + rr];
  }
  *(half8*)(VTh + (size_t)(d0 + rr) * N_TOK + n0 + cg * 16) = o0;
  *(half8*)(VTh + (size_t)(d0 + rr) * N_TOK + n0 + cg * 16 + 8) = o1;
}

// ---------------------------------------------------------------------------
// attn: flash attention with fused adj multiply.
// grid 256 WGs x 512 thr. blockIdx&7 -> (head, gsplit, strip parity): each XCD
// sticks to one head's K/VT (4MB -> fits per-XCD L2). 8 waves = 4 row-strips
// (16 Q rows each) x 2-way KV split; per wave 16 iters of BN=64.
// Partial (m,l,O) per gsplit to workspace; merge_kernel combines.
// ---------------------------------------------------------------------------
__global__ __launch_bounds__(512, 2) void attn_kernel(
    const float* __restrict__ adj, const _Float16* __restrict__ Q16,
    const _Float16* __restrict__ K16, const _Float16* __restrict__ VT16,
    _Float16* __restrict__ Opart, float* __restrict__ Mpart, float* __restrict__ Lpart)
{
  __shared__ __align__(16) _Float16 Pbuf[8 * 16 * 72];   // per-wave P staging
  __shared__ _Float16 Osh[4 * 16 * 260];                 // c=1 partial O
  __shared__ float Msh[64], Lsh[64];

  int b = blockIdx.x;
  int xcd = b & 7;
  int head = xcd >> 2;
  int gs = (xcd >> 1) & 1;
  int strip = ((b >> 3) << 1) | (xcd & 1);               // 0..63
  int q0 = strip * 64;

  int tid = threadIdx.x;
  int w = tid >> 6, lane = tid & 63, quad = lane >> 4, cL = lane & 15;
  int r = w >> 1, c = w & 1;

  const _Float16* Qh = Q16 + head * (N_TOK * D_HID);
  const _Float16* Kh = K16 + head * (N_TOK * D_HID);
  const _Float16* Vh = VT16 + head * (N_TOK * D_HID);
  const float* adjh = adj + (size_t)head * N_TOK * N_TOK;

  int qrow = q0 + r * 16;
  const f32x4 z4 = {0.f, 0.f, 0.f, 0.f};

  half8 qf[8];
#pragma unroll
  for (int t = 0; t < 8; t++)
    qf[t] = *(const half8*)(Qh + (qrow + cL) * D_HID + t * 32 + quad * 8);

  f32x4 acc[16];
#pragma unroll
  for (int i = 0; i < 16; i++) acc[i] = z4;
  float m_i[4] = {-1e30f, -1e30f, -1e30f, -1e30f};
  float l_i[4] = {0.f, 0.f, 0.f, 0.f};

  _Float16* pb = Pbuf + w * (16 * 72);
  const int nstart = gs * 2048 + c * 1024;

  const float* adjR[4];
#pragma unroll
  for (int reg = 0; reg < 4; reg++)
    adjR[reg] = adjh + (size_t)(qrow + quad * 4 + reg) * N_TOK + cL + nstart;

  for (int it = 0; it < 16; ++it) {
    int n0 = nstart + it * 64;
    int nl = it * 64;
    float av[4][4];
#pragma unroll
    for (int reg = 0; reg < 4; reg++)
#pragma unroll
      for (int ct = 0; ct < 4; ct++)
        av[reg][ct] = __builtin_nontemporal_load(adjR[reg] + nl + ct * 16);

    f32x4 s[4];
#pragma unroll
    for (int ct = 0; ct < 4; ct++) {
      s[ct] = z4;
      const _Float16* kp = Kh + (n0 + ct * 16 + cL) * D_HID + quad * 8;
#pragma unroll
      for (int t = 0; t < 8; t++) {
        half8 kf = *(const half8*)(kp + t * 32);
        s[ct] = __builtin_amdgcn_mfma_f32_16x16x32_f16(qf[t], kf, s[ct], 0, 0, 0);
      }
    }

    float alpha[4];
#pragma unroll
    for (int reg = 0; reg < 4; reg++) {
#pragma unroll
      for (int ct = 0; ct < 4; ct++) s[ct][reg] *= av[reg][ct];
      float mx = fmaxf(fmaxf(s[0][reg], s[1][reg]), fmaxf(s[2][reg], s[3][reg]));
#pragma unroll
      for (int msk = 1; msk < 16; msk <<= 1) mx = fmaxf(mx, __shfl_xor(mx, msk, 16));
      float mnew = fmaxf(m_i[reg], mx);
      alpha[reg] = __expf(m_i[reg] - mnew);
      m_i[reg] = mnew;
      float rs = 0.f;
#pragma unroll
      for (int ct = 0; ct < 4; ct++) {
        float p = __expf(s[ct][reg] - mnew);
        s[ct][reg] = p;
        rs += p;
      }
#pragma unroll
      for (int msk = 1; msk < 16; msk <<= 1) rs += __shfl_xor(rs, msk, 16);
      l_i[reg] = l_i[reg] * alpha[reg] + rs;
    }

    // P (C-layout) -> LDS row-major [16][72]
#pragma unroll
    for (int reg = 0; reg < 4; reg++)
#pragma unroll
      for (int ct = 0; ct < 4; ct++)
        pb[(quad * 4 + reg) * 72 + ct * 16 + cL] = (_Float16)s[ct][reg];

    // rescale O
#pragma unroll
    for (int dt = 0; dt < 16; dt++)
#pragma unroll
      for (int reg = 0; reg < 4; reg++)
        acc[dt][reg] *= alpha[reg];

    // P as A-frags (within-wave LDS ordering: no barrier needed)
    half8 pf0 = *(const half8*)(pb + cL * 72 + quad * 8);
    half8 pf1 = *(const half8*)(pb + cL * 72 + 32 + quad * 8);
    const _Float16* vp = Vh + (size_t)cL * N_TOK + n0 + quad * 8;
#pragma unroll
    for (int dt = 0; dt < 16; dt++) {
      half8 v0 = *(const half8*)(vp + (size_t)dt * 16 * N_TOK);
      half8 v1 = *(const half8*)(vp + (size_t)dt * 16 * N_TOK + 32);
      acc[dt] = __builtin_amdgcn_mfma_f32_16x16x32_f16(pf0, v0, acc[dt], 0, 0, 0);
      acc[dt] = __builtin_amdgcn_mfma_f32_16x16x32_f16(pf1, v1, acc[dt], 0, 0, 0);
    }
  }

  // 2-way in-WG merge across c
  if (c == 1) {
    if (cL == 0) {
#pragma unroll
      for (int reg = 0; reg < 4; reg++) {
        Msh[r * 16 + quad * 4 + reg] = m_i[reg];
        Lsh[r * 16 + quad * 4 + reg] = l_i[reg];
      }
    }
#pragma unroll
    for (int dt = 0; dt < 16; dt++)
#pragma unroll
      for (int reg = 0; reg < 4; reg++)
        Osh[(r * 16 + quad * 4 + reg) * 260 + dt * 16 + cL] = (_Float16)acc[dt][reg];
  }
  __syncthreads();
  if (c == 0) {
    int pbase = (head * 2 + gs) * N_TOK + qrow;
#pragma unroll
    for (int reg = 0; reg < 4; reg++) {
      float m1 = Msh[r * 16 + quad * 4 + reg];
      float l1 = Lsh[r * 16 + quad * 4 + reg];
      float mm = fmaxf(m_i[reg], m1);
      float f0 = __expf(m_i[reg] - mm), f1 = __expf(m1 - mm);
      float lf = f0 * l_i[reg] + f1 * l1;
      int row = pbase + quad * 4 + reg;
#pragma unroll
      for (int dt = 0; dt < 16; dt++) {
        float o = acc[dt][reg] * f0 +
                  (float)Osh[(r * 16 + quad * 4 + reg) * 260 + dt * 16 + cL] * f1;
        Opart[(size_t)row * D_HID + dt * 16 + cL] = (_Float16)o;
      }
      if (cL == 0) { Mpart[row] = mm; Lpart[row] = lf; }
    }
  }
}

// ---------------------------------------------------------------------------
// merge: combine the 2 global KV splits -> Xf [4096][512] fp16 (head concat)
// ---------------------------------------------------------------------------
__global__ void merge_kernel(const _Float16* __restrict__ Opart,
                             const float* __restrict__ Mpart,
                             const float* __restrict__ Lpart,
                             _Float16* __restrict__ Xf)
{
  int t = blockIdx.x * 256 + threadIdx.x;
  int dg = (t & 63) << 2;
  int n = (t >> 6) & (N_TOK - 1);
  int head = t >> 18;
  int i0 = (head * 2 + 0) * N_TOK + n;
  int i1 = (head * 2 + 1) * N_TOK + n;
  float m0 = Mpart[i0], m1 = Mpart[i1];
  float l0 = Lpart[i0], l1 = Lpart[i1];
  float mm = fmaxf(m0, m1);
  float f0 = __expf(m0 - mm), f1 = __expf(m1 - mm);
  float rl = 1.0f / (f0 * l0 + f1 * l1);
  half4 o0 = *(const half4*)(Opart + (size_t)i0 * D_HID + dg);
  half4 o1 = *(const half4*)(Opart + (size_t)i1 * D_HID + dg);
  half4 res;
#pragma unroll
  for (int u = 0; u < 4; u++)
    res[u] = (_Float16)((((float)o0[u]) * f0 + ((float)o1[u]) * f1) * rl);
  *(half4*)(Xf + (size_t)n * D_IN + head * D_HID + dg) = res;
}

// ---------------------------------------------------------------------------
// final: z = Xf@Wo + bo -> LayerNorm -> softmax(M@Wp + bp) -> out [4096][40]
// grid 128 x 256 thr; 32 rows/WG; 4 waves = 2 strips x 2 col halves
// ---------------------------------------------------------------------------
__global__ __launch_bounds__(256, 2) void final_kernel(
    const _Float16* __restrict__ Xf, const _Float16* __restrict__ Wot,
    const _Float16* __restrict__ Wpt, const float* __restrict__ bo,
    const float* __restrict__ gamma, const float* __restrict__ beta,
    const float* __restrict__ bp, float* __restrict__ out)
{
  __shared__ __align__(16) _Float16 Mlds[32 * 520];
  __shared__ float outs[32 * 48];
  __shared__ float lnsum[2][32], lnsq[2][32];
  __shared__ float smx[32], srl[32];

  int bIdx = blockIdx.x;
  int rowbase = bIdx * 32;
  int tid = threadIdx.x, w = tid >> 6, lane = tid & 63, quad = lane >> 4, cL = lane & 15;
  int r = w >> 1, ch = w & 1;
  const f32x4 z4 = {0.f, 0.f, 0.f, 0.f};

  half8 af[16];
#pragma unroll
  for (int t = 0; t < 16; t++)
    af[t] = *(const half8*)(Xf + (rowbase + r * 16 + cL) * D_IN + t * 32 + quad * 8);

  f32x4 acc[16];
#pragma unroll
  for (int i = 0; i < 16; i++) acc[i] = z4;
#pragma unroll
  for (int t = 0; t < 16; t++) {
#pragma unroll
    for (int nt = 0; nt < 16; nt++) {
      half8 bf = *(const half8*)(Wot + (ch * 256 + nt * 16 + cL) * D_IN + t * 32 + quad * 8);
      acc[nt] = __builtin_amdgcn_mfma_f32_16x16x32_f16(af[t], bf, acc[nt], 0, 0, 0);
    }
  }

  float sum[4] = {0, 0, 0, 0}, sq[4] = {0, 0, 0, 0};
#pragma unroll
  for (int nt = 0; nt < 16; nt++) {
    int col = ch * 256 + nt * 16 + cL;
    float bb = bo[col];
#pragma unroll
    for (int reg = 0; reg < 4; reg++) {
      float z = acc[nt][reg] + bb;
      acc[nt][reg] = z;
      sum[reg] += z;
      sq[reg] += z * z;
    }
  }
#pragma unroll
  for (int reg = 0; reg < 4; reg++) {
#pragma unroll
    for (int msk = 1; msk < 16; msk <<= 1) {
      sum[reg] += __shfl_xor(sum[reg], msk, 16);
      sq[reg]  += __shfl_xor(sq[reg], msk, 16);
    }
  }
  if (cL == 0) {
#pragma unroll
    for (int reg = 0; reg < 4; reg++) {
      lnsum[ch][r * 16 + quad * 4 + reg] = sum[reg];
      lnsq[ch][r * 16 + quad * 4 + reg]  = sq[reg];
    }
  }
  __syncthreads();
  float mean[4], rstd[4];
#pragma unroll
  for (int reg = 0; reg < 4; reg++) {
    int row = r * 16 + quad * 4 + reg;
    float s  = lnsum[0][row] + lnsum[1][row];
    float s2 = lnsq[0][row]  + lnsq[1][row];
    float mu = s * (1.0f / 512.0f);
    float var = s2 * (1.0f / 512.0f) - mu * mu;
    mean[reg] = mu;
    rstd[reg] = rsqrtf(var + 1e-5f);
  }
#pragma unroll
  for (int nt = 0; nt < 16; nt++) {
    int col = ch * 256 + nt * 16 + cL;
    float g = gamma[col], be = beta[col];
#pragma unroll
    for (int reg = 0; reg < 4; reg++) {
      float mval = (acc[nt][reg] - mean[reg]) * rstd[reg] * g + be;
      Mlds[(r * 16 + quad * 4 + reg) * 520 + col] = (_Float16)mval;
    }
  }
  __syncthreads();
  int njt = (ch == 0) ? 2 : 1;
  for (int jj = 0; jj < njt; jj++) {
    int jt = ch * 2 + jj;                      // ch0: 0,1  ch1: 2
    f32x4 a2 = z4;
#pragma unroll
    for (int t = 0; t < 16; t++) {
      half8 am = *(const half8*)(Mlds + (r * 16 + cL) * 520 + t * 32 + quad * 8);
      half8 bm = *(const half8*)(Wpt + (jt * 16 + cL) * D_IN + t * 32 + quad * 8);
      a2 = __builtin_amdgcn_mfma_f32_16x16x32_f16(am, bm, a2, 0, 0, 0);
    }
    int col = jt * 16 + cL;
    float bpv = (col < N_OUT) ? bp[col] : 0.0f;
#pragma unroll
    for (int reg = 0; reg < 4; reg++)
      outs[(r * 16 + quad * 4 + reg) * 48 + col] = a2[reg] + bpv;
  }
  __syncthreads();
  if (tid < 32) {
    int row = tid;
    float mx = -1e30f;
    for (int j = 0; j < N_OUT; j++) mx = fmaxf(mx, outs[row * 48 + j]);
    float ssum = 0.f;
    for (int j = 0; j < N_OUT; j++) ssum += __expf(outs[row * 48 + j] - mx);
    smx[row] = mx;
    srl[row] = 1.0f / ssum;
  }
  __syncthreads();
#pragma unroll
  for (int i = 0; i < 5; i++) {
    int lin = tid + 256 * i;                   // 0..1279 = 32 rows x 40 cols
    int row = lin / 40, col = lin % 40;
    out[(size_t)(rowbase + row) * N_OUT + col] =
        __expf(outs[row * 48 + col] - smx[row]) * srl[row];
  }
}

// ---------------------------------------------------------------------------
// Workspace layout (bytes, all 256-aligned), total ~34.2 MB
// ---------------------------------------------------------------------------
#define OFF_H16   0u
#define OFF_WQT   4194304u
#define OFF_WKT   4718592u
#define OFF_WVT   5242880u
#define OFF_WOT   5767168u
#define OFF_WPT   6291456u
#define OFF_Q16   6340608u
#define OFF_K16   10534912u
#define OFF_V16   14729216u
#define OFF_VT16  18923520u
#define OFF_OP    23117824u
#define OFF_MP    31506432u
#define OFF_LP    31571968u
#define OFF_XF    31637504u

extern "C" void kernel_launch(void* const* d_in, const int* in_sizes, int n_in,
                              void* d_out, int out_size, void* d_ws, size_t ws_size,
                              hipStream_t stream)
{
  const float* adj   = (const float*)d_in[0];
  const float* h     = (const float*)d_in[1];
  const float* Wq    = (const float*)d_in[2];
  const float* bq    = (const float*)d_in[3];
  const float* Wk    = (const float*)d_in[4];
  const float* bk    = (const float*)d_in[5];
  const float* Wv    = (const float*)d_in[6];
  const float* bv    = (const float*)d_in[7];
  const float* Wo    = (const float*)d_in[8];
  const float* bo    = (const float*)d_in[9];
  const float* gamma = (const float*)d_in[10];
  const float* beta  = (const float*)d_in[11];
  const float* Wp    = (const float*)d_in[12];
  const float* bp    = (const float*)d_in[13];
  float* out = (float*)d_out;
  char* ws = (char*)d_ws;

  _Float16* h16   = (_Float16*)(ws + OFF_H16);
  _Float16* Wqt   = (_Float16*)(ws + OFF_WQT);
  _Float16* Wkt   = (_Float16*)(ws + OFF_WKT);
  _Float16* Wvt   = (_Float16*)(ws + OFF_WVT);
  _Float16* Wot   = (_Float16*)(ws + OFF_WOT);
  _Float16* Wpt   = (_Float16*)(ws + OFF_WPT);
  _Float16* Q16   = (_Float16*)(ws + OFF_Q16);
  _Float16* K16   = (_Float16*)(ws + OFF_K16);
  _Float16* V16   = (_Float16*)(ws + OFF_V16);
  _Float16* VT16  = (_Float16*)(ws + OFF_VT16);
  _Float16* Opart = (_Float16*)(ws + OFF_OP);
  float*    Mpart = (float*)(ws + OFF_MP);
  float*    Lpart = (float*)(ws + OFF_LP);
  _Float16* Xf    = (_Float16*)(ws + OFF_XF);

  prep_kernel<<<2072, 256, 0, stream>>>(h, Wq, Wk, Wv, Wo, Wp,
                                        h16, Wqt, Wkt, Wvt, Wot, Wpt);
  proj_kernel<<<768, 256, 0, stream>>>(h16, Wqt, Wkt, Wvt, bq, bk, bv,
                                       Q16, K16, V16);
  transv_kernel<<<512, 256, 0, stream>>>(V16, VT16);
  attn_kernel<<<256, 512, 0, stream>>>(adj, Q16, K16, VT16, Opart, Mpart, Lpart);
  merge_kernel<<<2048, 256, 0, stream>>>(Opart, Mpart, Lpart, Xf);
  final_kernel<<<128, 256, 0, stream>>>(Xf, Wot, Wpt, bo, gamma, beta, bp, out);
}